// Round 5
// baseline (151.138 us; speedup 1.0000x reference)
//
#include <hip/hip_runtime.h>
#include <math.h>

// Problem constants: B=32, C=64, H=128, W=128
#define HW 16384     // 128*128 plane elements
#define NPLANE 2048  // B*C planes

typedef __bf16 bf16x8 __attribute__((ext_vector_type(8)));
typedef float  f32x4  __attribute__((ext_vector_type(4)));

// ---------------------------------------------------------------------------
// 2D WHT(128x128) == 1D WHT(16384) over the flattened plane (H2^(x)14).
// 512 threads/plane, 32 elems/thread (8 float4).
// Phase A: bits {0,1} (in-quad) + {11,12,13} (regs)   [global -> regs -> LDS]
// Phase B: bits {2,3} (in-quad) + {4,5,6}  (regs)     [LDS in-place, b128]
// Phase C: bits {7,8} (in-quad) + {9,10}   (regs)     [LDS gather b32]
// LDS layout P(i): bit0=i2 1=i3 2=i0^i4 3=i1^i5 4=i7^i6 5=i8 6=i9 7=i10
//                  8=i4 9=i5 10=i6 11=i11 12=i12 13=i13
// -> A-store, B-load/store, C-gather are all exactly 2-way banked (free).
// ---------------------------------------------------------------------------

__device__ __forceinline__ void bf_quad(float4& a) {
    float s0 = a.x + a.y, d0 = a.x - a.y;
    float s1 = a.z + a.w, d1 = a.z - a.w;
    a.x = s0 + s1; a.y = d0 + d1; a.z = s0 - s1; a.w = d0 - d1;
}

__device__ __forceinline__ void bf_pair(float4& a, float4& b) {
    float4 s, d;
    s.x = a.x + b.x; s.y = a.y + b.y; s.z = a.z + b.z; s.w = a.w + b.w;
    d.x = a.x - b.x; d.y = a.y - b.y; d.z = a.z - b.z; d.w = a.w - b.w;
    a = s; b = d;
}

__device__ __forceinline__ void bf_regs3(float4 (&r)[8]) {
    #pragma unroll
    for (int m = 1; m <= 4; m <<= 1) {
        #pragma unroll
        for (int j = 0; j < 8; ++j) {
            if (!(j & m)) bf_pair(r[j], r[j | m]);
        }
    }
}

// Full 14-stage WHT; result in r with element mapping:
//   (i7,i8) = float4 component (lsb-first), (i9,i10) = j&3, i0 = j>>2,
//   (i1..i6) = t&63, (i11,i12,i13) = t>>6.
__device__ __forceinline__ void wht14(const float* __restrict__ src,
                                      float* __restrict__ lds,
                                      float4 (&r)[8], int t) {
    // ---- Phase A ----
    const float4* s4 = reinterpret_cast<const float4*>(src);
    #pragma unroll
    for (int j = 0; j < 8; ++j) r[j] = s4[t + j * 512];
    #pragma unroll
    for (int j = 0; j < 8; ++j) bf_quad(r[j]);      // bits 0,1
    bf_regs3(r);                                     // bits 11,12,13

    {   // store: thread bits i2..i10 = t0..t8; elem: (i0,i1)=comp, j=(i11,12,13)
        const int physT = (t & 3)                                  // i2,i3
                        + ((((t >> 5) ^ (t >> 4)) & 1) << 4)       // i7^i6
                        + (((t >> 6) & 7) << 5)                    // i8,i9,i10
                        + (((t >> 2) & 7) << 8);                   // i4,i5,i6
        const int swc = (t >> 2) & 3;                              // (i4,i5)
        #pragma unroll
        for (int j = 0; j < 8; ++j) {
            float* b = lds + physT + j * 2048;
            b[(0 ^ swc) << 2] = r[j].x;
            b[(1 ^ swc) << 2] = r[j].y;
            b[(2 ^ swc) << 2] = r[j].z;
            b[(3 ^ swc) << 2] = r[j].w;
        }
    }
    __syncthreads();

    // ---- Phase B (in-place) ----
    {   // thread bits: i0,i1,i7,i8,i9,i10 = t0..t5; regs j = (i4,i5,i6)
        const int baseT = ((t & 63) << 2) + ((t >> 6) << 11);
        int addr[8];
        #pragma unroll
        for (int j = 0; j < 8; ++j) {
            addr[j] = (baseT ^ ((j & 3) << 2) ^ ((j >> 2) << 4)) + (j << 8);
            r[j] = *reinterpret_cast<const float4*>(lds + addr[j]);
        }
        #pragma unroll
        for (int j = 0; j < 8; ++j) bf_quad(r[j]);  // bits 2,3
        bf_regs3(r);                                 // bits 4,5,6
        #pragma unroll
        for (int j = 0; j < 8; ++j)
            *reinterpret_cast<float4*>(lds + addr[j]) = r[j];
    }
    __syncthreads();

    // ---- Phase C (gather) ----
    {   // thread bits: i1..i6 = t0..t5; elem: (i7,i8)=comp, (i9,i10)=j&3, i0=j>>2
        const int t0 = t & 1, t1 = (t >> 1) & 1, t2 = (t >> 2) & 1;
        const int t3 = (t >> 3) & 1, t4 = (t >> 4) & 1, t5 = (t >> 5) & 1;
        const int cT = t1 + (t2 << 1) + ((t0 ^ t4) << 3)
                     + (t3 << 8) + (t4 << 9) + (t5 << 10) + ((t >> 6) << 11);
        #pragma unroll
        for (int j = 0; j < 8; ++j) {
            const int a = cT + ((((j >> 2) ^ t3)) << 2)
                        + ((j & 1) << 6) + (((j >> 1) & 1) << 7);
            float4 q;
            q.x = lds[a + ((0 ^ t5) << 4)];            // (i7,i8)=(0,0)
            q.y = lds[a + ((1 ^ t5) << 4)];            // (1,0)
            q.z = lds[a + ((0 ^ t5) << 4) + (1 << 5)]; // (0,1)
            q.w = lds[a + ((1 ^ t5) << 4) + (1 << 5)]; // (1,1)
            r[j] = q;
        }
        #pragma unroll
        for (int j = 0; j < 8; ++j) bf_quad(r[j]);  // bits 7,8
        #pragma unroll
        for (int m = 1; m <= 2; m <<= 1) {          // bits 9,10 (j-bit2 = i0: done)
            #pragma unroll
            for (int j = 0; j < 8; ++j) {
                if (!(j & m)) bf_pair(r[j], r[j | m]);
            }
        }
    }
}

__global__ __launch_bounds__(512) void k_wht2d_fwd(const float* __restrict__ x,
                                                   float* __restrict__ out) {
    __shared__ float lds[HW];  // 64 KiB
    const int t = threadIdx.x;
    const size_t plane = (size_t)blockIdx.x * HW;

    float4 r[8];
    wht14(x + plane, lds, r, t);

    float* dst = out + plane;
    const int dT = ((t & 63) << 1) + ((t >> 6) << 11);
    #pragma unroll
    for (int j = 0; j < 4; ++j) {
        const int jb = dT + ((j & 1) << 9) + ((j >> 1) << 10);
        const float* lo = reinterpret_cast<const float*>(&r[j]);
        const float* hi = reinterpret_cast<const float*>(&r[j + 4]);
        #pragma unroll
        for (int c = 0; c < 4; ++c) {
            const int d = jb + ((c & 1) << 7) + ((c >> 1) << 8);
            float2 o; o.x = lo[c]; o.y = hi[c];
            *reinterpret_cast<float2*>(dst + d) = o;
        }
    }
}

__global__ __launch_bounds__(512) void k_wht2d_inv(float* __restrict__ buf,
                                                   const float* __restrict__ x) {
    __shared__ float lds[HW];
    const int t = threadIdx.x;
    const size_t plane = (size_t)blockIdx.x * HW;

    float4 r[8];
    wht14(buf + plane, lds, r, t);

    float* dst = buf + plane;
    const float* xr = x + plane;
    const float s = 1.0f / 16384.0f;
    const int dT = ((t & 63) << 1) + ((t >> 6) << 11);
    #pragma unroll
    for (int j = 0; j < 4; ++j) {
        const int jb = dT + ((j & 1) << 9) + ((j >> 1) << 10);
        const float* lo = reinterpret_cast<const float*>(&r[j]);
        const float* hi = reinterpret_cast<const float*>(&r[j + 4]);
        #pragma unroll
        for (int c = 0; c < 4; ++c) {
            const int d = jb + ((c & 1) << 7) + ((c >> 1) << 8);
            float2 xv = *reinterpret_cast<const float2*>(xr + d);
            float2 o;
            o.x = lo[c] * s + xv.x;
            o.y = hi[c] * s + xv.y;
            *reinterpret_cast<float2*>(dst + d) = o;
        }
    }
}

// ---------------------------------------------------------------------------
// Channel mix via bf16 MFMA (unchanged from R3): per b,
// Out = W(64x64) . (v .* f2)(64 x 16384), soft-threshold fused, in-place.
// ---------------------------------------------------------------------------
__global__ __launch_bounds__(256) void k_mix_mfma(float* __restrict__ buf,
                                                  const float* __restrict__ W,
                                                  const float* __restrict__ v,
                                                  const float* __restrict__ T) {
    __shared__ float Xs[64 * 128];  // 32 KiB
    const int t = threadIdx.x;
    const int l = t & 63, w = t >> 6;
    const int b  = blockIdx.x >> 7;
    const int p0 = (blockIdx.x & 127) << 7;
    float* base = buf + (size_t)b * 64 * HW + p0;

    bf16x8 A[4][2];
    {
        const int row = l & 15;
        const int kc  = (l >> 4) * 8;
        #pragma unroll
        for (int mt = 0; mt < 4; ++mt) {
            const float* wr = W + (mt * 16 + row) * 64 + kc;
            #pragma unroll
            for (int ks = 0; ks < 2; ++ks) {
                float4 w0 = *reinterpret_cast<const float4*>(wr + ks * 32);
                float4 w1 = *reinterpret_cast<const float4*>(wr + ks * 32 + 4);
                bf16x8 a;
                a[0] = (__bf16)w0.x; a[1] = (__bf16)w0.y;
                a[2] = (__bf16)w0.z; a[3] = (__bf16)w0.w;
                a[4] = (__bf16)w1.x; a[5] = (__bf16)w1.y;
                a[6] = (__bf16)w1.z; a[7] = (__bf16)w1.w;
                A[mt][ks] = a;
            }
        }
    }

    #pragma unroll
    for (int i = 0; i < 8; ++i) {
        const int d  = i * 1024 + t * 4;
        const int c  = d >> 7;
        const int pq = d & 127;
        float4 xv = *reinterpret_cast<const float4*>(base + (size_t)c * HW + pq);
        float4 vv = *reinterpret_cast<const float4*>(v + p0 + pq);
        float4 r;
        r.x = xv.x * vv.x; r.y = xv.y * vv.y;
        r.z = xv.z * vv.z; r.w = xv.w * vv.w;
        const int gc = (c >> 3) & 3;
        *reinterpret_cast<float4*>(Xs + c * 128 + (pq ^ (gc << 4))) = r;
    }
    __syncthreads();

    f32x4 acc[4][2] = {};
    const int n0 = w * 32;
    const int g  = l >> 4;
    #pragma unroll
    for (int nt = 0; nt < 2; ++nt) {
        const int pl = n0 + nt * 16 + (l & 15);
        #pragma unroll
        for (int ks = 0; ks < 2; ++ks) {
            const float* col = Xs + (ks * 32 + g * 8) * 128 + (pl ^ (g << 4));
            bf16x8 bb;
            #pragma unroll
            for (int j = 0; j < 8; ++j) bb[j] = (__bf16)col[j * 128];
            #pragma unroll
            for (int mt = 0; mt < 4; ++mt)
                acc[mt][nt] = __builtin_amdgcn_mfma_f32_16x16x32_bf16(
                    A[mt][ks], bb, acc[mt][nt], 0, 0, 0);
        }
    }

    #pragma unroll
    for (int nt = 0; nt < 2; ++nt) {
        const int p  = p0 + n0 + nt * 16 + (l & 15);
        const float Tp = fmaxf(T[p], 0.0f);
        #pragma unroll
        for (int mt = 0; mt < 4; ++mt) {
            #pragma unroll
            for (int r = 0; r < 4; ++r) {
                const int o = mt * 16 + g * 4 + r;
                float val = acc[mt][nt][r];
                float mag = fmaxf(fabsf(val) - Tp, 0.0f);
                buf[(size_t)b * 64 * HW + (size_t)o * HW + p] = copysignf(mag, val);
            }
        }
    }
}

extern "C" void kernel_launch(void* const* d_in, const int* in_sizes, int n_in,
                              void* d_out, int out_size, void* d_ws, size_t ws_size,
                              hipStream_t stream) {
    const float* x = (const float*)d_in[0];
    const float* W = (const float*)d_in[1];
    const float* v = (const float*)d_in[2];
    const float* T = (const float*)d_in[3];
    float* out = (float*)d_out;

    // f2 = WHT2D(x) -> d_out
    k_wht2d_fwd<<<NPLANE, 512, 0, stream>>>(x, out);
    // f6 = soft_threshold(W @ (v .* f2), T) -> d_out (in place)
    k_mix_mfma<<<32 * 128, 256, 0, stream>>>(out, W, v, T);
    // y = WHT2D(f6)/16384 + x -> d_out (in place)
    k_wht2d_inv<<<NPLANE, 512, 0, stream>>>(out, x);
}